// Round 2
// baseline (21598.875 us; speedup 1.0000x reference)
//
#include <hip/hip_runtime.h>
#include <hip/hip_bf16.h>
#include <stdint.h>

// a3c_lstm_ga forward, MI355X. All float tensors are FLOAT32 (possibly
// bf16-rounded values); ints are int32. Output d_out is float32:
// [critic(1), actor(4), hx_new(768), cx_new(768)] = 1541 floats.
//
// Bug-faithful reference: only attn[0] (curr branch) is consumed -> prev/next
// GRU scans are dead code. One scan only.
//
// GRU scan = serial floor: 2048 dependent steps of a 256->768 matvec on ONE CU.
// W_hh is packed f32->bf16 (lossless if data is bf16-rounded) so row t fits in
// 128 VGPRs of thread t; h stays f32 in LDS; gates exchanged via LDS.

typedef unsigned short bfraw;

__device__ __forceinline__ float bflo(uint32_t p) { return __uint_as_float(p << 16); }
__device__ __forceinline__ float bfhi(uint32_t p) { return __uint_as_float(p & 0xffff0000u); }
__device__ __forceinline__ float sigm(float x) { return 1.0f / (1.0f + __expf(-x)); }
__device__ __forceinline__ float tanh_f(float x) { return 2.0f / (1.0f + __expf(-2.0f * x)) - 1.0f; }
__device__ __forceinline__ uint32_t f2bf_rne(float f) {
    uint32_t u = __float_as_uint(f);
    return (u + 0x7fffu + ((u >> 16) & 1u)) >> 16;  // round-to-nearest-even
}

// ---------------- pack W_hh f32 -> bf16 pairs ----------------
__global__ void k_pack(const float* __restrict__ whh, uint32_t* __restrict__ whhp) {
    int i = blockIdx.x * 256 + threadIdx.x;  // 98304 pairs
    if (i >= 98304) return;
    uint32_t lo = f2bf_rne(whh[2 * i]);
    uint32_t hi = f2bf_rne(whh[2 * i + 1]);
    whhp[i] = lo | (hi << 16);
}

// ---------------- conv tower ----------------
// conv1: x[3,124,124] * w[128,3,8,8] s4 -> relu -> h1[128,30,30]
__global__ void k_conv1(const float* __restrict__ x, const float* __restrict__ w,
                        const float* __restrict__ b, float* __restrict__ h1) {
    int idx = blockIdx.x * 256 + threadIdx.x;
    if (idx >= 128 * 30 * 30) return;
    int ox = idx % 30, oy = (idx / 30) % 30, oc = idx / 900;
    const float* wr = w + oc * 192;
    float acc = b[oc];
    for (int c = 0; c < 3; ++c)
        for (int ky = 0; ky < 8; ++ky) {
            const float* xr = x + (c * 124 + oy * 4 + ky) * 124 + ox * 4;
            const float* wk = wr + (c * 8 + ky) * 8;
#pragma unroll
            for (int kx = 0; kx < 8; ++kx) acc = fmaf(xr[kx], wk[kx], acc);
        }
    h1[idx] = fmaxf(acc, 0.0f);
}

// conv2: h1[128,30,30] * w[64,128,4,4] s2 -> relu -> h2[64,14,14]
__global__ void k_conv2(const float* __restrict__ h1, const float* __restrict__ w,
                        const float* __restrict__ b, float* __restrict__ h2) {
    int idx = blockIdx.x * 256 + threadIdx.x;
    if (idx >= 64 * 14 * 14) return;
    int ox = idx % 14, oy = (idx / 14) % 14, oc = idx / 196;
    float acc = b[oc];
    const float* wr = w + oc * 128 * 16;
    for (int c = 0; c < 128; ++c) {
#pragma unroll
        for (int ky = 0; ky < 4; ++ky) {
            const float* hr = h1 + (c * 30 + oy * 2 + ky) * 30 + ox * 2;
            const float* wk = wr + (c * 4 + ky) * 4;
#pragma unroll
            for (int kx = 0; kx < 4; ++kx) acc = fmaf(hr[kx], wk[kx], acc);
        }
    }
    h2[idx] = fmaxf(acc, 0.0f);
}

// conv3: h2[64,14,14] * w[64,64,4,4] s2 -> relu -> x3[64,6,6]
__global__ void k_conv3(const float* __restrict__ h2, const float* __restrict__ w,
                        const float* __restrict__ b, float* __restrict__ x3) {
    int idx = blockIdx.x * 256 + threadIdx.x;
    if (idx >= 64 * 6 * 6) return;
    int ox = idx % 6, oy = (idx / 6) % 6, oc = idx / 36;
    float acc = b[oc];
    const float* wr = w + oc * 64 * 16;
    for (int c = 0; c < 64; ++c) {
#pragma unroll
        for (int ky = 0; ky < 4; ++ky) {
            const float* hr = h2 + (c * 14 + oy * 2 + ky) * 14 + ox * 2;
            const float* wk = wr + (c * 4 + ky) * 4;
#pragma unroll
            for (int kx = 0; kx < 4; ++kx) acc = fmaf(hr[kx], wk[kx], acc);
        }
    }
    x3[idx] = fmaxf(acc, 0.0f);
}

// ---------------- GRU input-gate precompute (curr only) ----------------
// gi[t][j] = emb[tok_t] . w_ih[j] + b_ih[j]
__global__ void k_gi(const int* __restrict__ curr, const float* __restrict__ emb,
                     const float* __restrict__ wih, const float* __restrict__ bih,
                     float* __restrict__ gi) {
    int idx = blockIdx.x * 256 + threadIdx.x;  // 2048*768
    int j = idx % 768, t = idx / 768;
    int tok = curr[t];
    const float* e = emb + tok * 32;
    const float* wr = wih + j * 32;
    float acc = bih[j];
#pragma unroll
    for (int k = 0; k < 32; ++k) acc = fmaf(e[k], wr[k], acc);
    gi[idx] = acc;
}

// ---------------- GRU scan (single block, 2048 sequential steps) ----------------
__global__ __launch_bounds__(768) void k_gru_scan(
    const float* __restrict__ gi, const uint32_t* __restrict__ whhp,
    const float* __restrict__ bhh, const float* __restrict__ attn_w,
    const float* __restrict__ attn_b, float* __restrict__ attn0) {
    __shared__ __align__(16) float hs[256];
    __shared__ float zs[256], gia[256], gha[256];
    const int t = threadIdx.x;

    // cache packed W_hh row t: 256 bf16 = 128 uint32 in VGPRs
    uint32_t wreg[128];
    {
        const uint4* wp = (const uint4*)(whhp + (size_t)t * 128);
        uint4* wd = (uint4*)wreg;
#pragma unroll
        for (int i = 0; i < 32; ++i) wd[i] = wp[i];
    }
    const float bh = bhh[t];
    if (t < 256) hs[t] = 0.0f;
    float giv = gi[t];  // step 0 input gates
    __syncthreads();

    for (int step = 0; step < 2048; ++step) {
        // prefetch next step's gi so its latency hides under the dot loop
        float ginext = (step < 2047) ? gi[(size_t)(step + 1) * 768 + t] : 0.0f;

        float a0 = 0.f, a1 = 0.f, a2 = 0.f, a3 = 0.f;
#pragma unroll
        for (int k = 0; k < 256; k += 8) {
            const float4 hA = *(const float4*)(hs + k);
            const float4 hB = *(const float4*)(hs + k + 4);
            uint32_t p0 = wreg[k / 2 + 0], p1 = wreg[k / 2 + 1];
            uint32_t p2 = wreg[k / 2 + 2], p3 = wreg[k / 2 + 3];
            a0 = fmaf(bflo(p0), hA.x, a0);
            a1 = fmaf(bfhi(p0), hA.y, a1);
            a2 = fmaf(bflo(p1), hA.z, a2);
            a3 = fmaf(bfhi(p1), hA.w, a3);
            a0 = fmaf(bflo(p2), hB.x, a0);
            a1 = fmaf(bfhi(p2), hB.y, a1);
            a2 = fmaf(bflo(p3), hB.z, a2);
            a3 = fmaf(bfhi(p3), hB.w, a3);
        }
        const float hpart = bh + ((a0 + a1) + (a2 + a3));  // row t of h@W_hh.T + b_hh
        const float g = giv + hpart;

        float rv = sigm(g);  // valid as r for t<256, as z for t in [256,512)
        if (t >= 512) {      // n-rows: publish i_n and h_n
            gia[t - 512] = giv;
            gha[t - 512] = hpart;
        } else if (t >= 256) {  // z-rows
            zs[t - 256] = rv;
        }
        __syncthreads();
        if (t < 256) {
            float n = tanh_f(fmaf(rv, gha[t], gia[t]));
            float z = zs[t];
            hs[t] = fmaf(z, hs[t] - n, n);  // (1-z)*n + z*h
        }
        giv = ginext;
        __syncthreads();
    }

    // fused attention head: attn0[j] = sigm(attn_w[j] . h + attn_b[j]), j<64
    if (t < 64) {
        const float* ar = attn_w + t * 256;
        float acc = attn_b[t];
        for (int k = 0; k < 256; ++k) acc = fmaf(ar[k], hs[k], acc);
        attn0[t] = sigm(acc);
    }
}

// ---------------- fuse + linear: feat[256] = relu(lin_w @ (x3*attn) + lin_b) ----
__global__ void k_feat(const float* __restrict__ x3, const float* __restrict__ attn0,
                       const float* __restrict__ lw, const float* __restrict__ lb,
                       float* __restrict__ feat) {
    __shared__ __align__(16) float fused[2304];
    int t = threadIdx.x;  // 64 threads
    for (int i = t; i < 2304; i += 64) fused[i] = x3[i] * attn0[i / 36];
    __syncthreads();
    int row = blockIdx.x * 64 + t;  // 256 rows over 4 blocks
    const float4* wv = (const float4*)(lw + (size_t)row * 2304);
    float acc = lb[row];
    for (int i = 0; i < 576; ++i) {  // 576 * 4 f32 = 2304
        float4 v = wv[i];
        const float* f = fused + i * 4;
        acc = fmaf(v.x, f[0], acc);
        acc = fmaf(v.y, f[1], acc);
        acc = fmaf(v.z, f[2], acc);
        acc = fmaf(v.w, f[3], acc);
    }
    feat[row] = fmaxf(acc, 0.0f);
}

// ---------------- LSTM gates: wave-per-row, xcat = [feat,feat,feat] ----------------
__global__ void k_lstm_gates(const float* __restrict__ wih, const float* __restrict__ whh,
                             const float* __restrict__ bih, const float* __restrict__ bhh,
                             const float* __restrict__ hx, const float* __restrict__ feat,
                             float* __restrict__ gates) {
    int wid = threadIdx.x >> 6, lane = threadIdx.x & 63;
    int row = blockIdx.x * 4 + wid;  // < 3072
    const float* wi = wih + (size_t)row * 768;
    const float* wh = whh + (size_t)row * 768;
    float acc = 0.0f;
#pragma unroll
    for (int i = 0; i < 12; ++i) {
        int k = lane + i * 64;
        acc = fmaf(wi[k], feat[k & 255], acc);  // xcat[k] = feat[k % 256]
        acc = fmaf(wh[k], hx[k], acc);
    }
#pragma unroll
    for (int s = 32; s; s >>= 1) acc += __shfl_down(acc, s, 64);
    if (lane == 0) gates[row] = acc + bih[row] + bhh[row];
}

// ---------------- LSTM cell elementwise + output writes ----------------
__global__ void k_lstm_cell(const float* __restrict__ gates, const float* __restrict__ cx,
                            float* __restrict__ out, float* __restrict__ hxf) {
    int i = threadIdx.x;  // 768
    float g_i = gates[i], g_f = gates[768 + i], g_g = gates[1536 + i], g_o = gates[2304 + i];
    float c = cx[i];
    float cn = sigm(g_f) * c + sigm(g_i) * tanh_f(g_g);
    float hn = sigm(g_o) * tanh_f(cn);
    out[5 + i] = hn;
    out[5 + 768 + i] = cn;
    hxf[i] = hn;
}

// ---------------- heads: z=[hx_new, time_emb[tx]] (800) -> critic(1), actor(4) ----
__global__ void k_heads(const float* __restrict__ hxf, const float* __restrict__ temb,
                        const int* __restrict__ tx, const float* __restrict__ cw,
                        const float* __restrict__ cb, const float* __restrict__ aw,
                        const float* __restrict__ ab, float* __restrict__ out) {
    __shared__ float z[800];
    int t = threadIdx.x;  // 320 = 5 waves
    for (int i = t; i < 768; i += 320) z[i] = hxf[i];
    if (t < 32) z[768 + t] = temb[tx[0] * 32 + t];
    __syncthreads();
    int w = t >> 6, lane = t & 63;
    const float* row = (w == 0) ? cw : (aw + (size_t)(w - 1) * 800);
    float acc = 0.0f;
    for (int k = lane; k < 800; k += 64) acc = fmaf(row[k], z[k], acc);
#pragma unroll
    for (int s = 32; s; s >>= 1) acc += __shfl_down(acc, s, 64);
    if (lane == 0) {
        float b = (w == 0) ? cb[0] : ab[w - 1];
        out[w] = acc + b;  // out[0]=critic, out[1..4]=actor
    }
}

extern "C" void kernel_launch(void* const* d_in, const int* in_sizes, int n_in,
                              void* d_out, int out_size, void* d_ws, size_t ws_size,
                              hipStream_t stream) {
    const float* x = (const float*)d_in[0];
    const int* curr = (const int*)d_in[1];
    // d_in[2] (prev_instr), d_in[3] (next_instr): dead code in the reference
    const int* tx = (const int*)d_in[4];
    const float* hx = (const float*)d_in[5];
    const float* cx = (const float*)d_in[6];
    const float* c1w = (const float*)d_in[7];
    const float* c1b = (const float*)d_in[8];
    const float* c2w = (const float*)d_in[9];
    const float* c2b = (const float*)d_in[10];
    const float* c3w = (const float*)d_in[11];
    const float* c3b = (const float*)d_in[12];
    const float* emb = (const float*)d_in[13];
    const float* temb = (const float*)d_in[14];
    const float* gwih = (const float*)d_in[15];
    const float* gwhh = (const float*)d_in[16];
    const float* gbih = (const float*)d_in[17];
    const float* gbhh = (const float*)d_in[18];
    const float* attw = (const float*)d_in[19];
    const float* attb = (const float*)d_in[20];
    const float* linw = (const float*)d_in[21];
    const float* linb = (const float*)d_in[22];
    const float* lwih = (const float*)d_in[23];
    const float* lwhh = (const float*)d_in[24];
    const float* lbih = (const float*)d_in[25];
    const float* lbhh = (const float*)d_in[26];
    const float* cw = (const float*)d_in[27];
    const float* cb = (const float*)d_in[28];
    const float* aw = (const float*)d_in[29];
    const float* ab = (const float*)d_in[30];
    float* out = (float*)d_out;

    // workspace layout (bytes, 16B aligned)
    char* ws = (char*)d_ws;
    float* gi = (float*)(ws + 0);                // 2048*768 f32 = 6291456 B
    float* h1 = (float*)(ws + 6291456);          // 115200 f32
    float* h2 = (float*)(ws + 6752256);          // 12544 f32
    float* x3 = (float*)(ws + 6802432);          // 2304 f32
    float* attn0 = (float*)(ws + 6811648);       // 64 f32
    float* feat = (float*)(ws + 6811904);        // 256 f32
    float* gates = (float*)(ws + 6812928);       // 3072 f32
    float* hxf = (float*)(ws + 6825216);         // 768 f32
    uint32_t* whhp = (uint32_t*)(ws + 6828288);  // 98304 u32 (packed bf16 W_hh)

    k_pack<<<384, 256, 0, stream>>>(gwhh, whhp);
    k_gi<<<6144, 256, 0, stream>>>(curr, emb, gwih, gbih, gi);
    k_conv1<<<450, 256, 0, stream>>>(x, c1w, c1b, h1);
    k_conv2<<<49, 256, 0, stream>>>(h1, c2w, c2b, h2);
    k_conv3<<<9, 256, 0, stream>>>(h2, c3w, c3b, x3);
    k_gru_scan<<<1, 768, 0, stream>>>(gi, whhp, gbhh, attw, attb, attn0);
    k_feat<<<4, 64, 0, stream>>>(x3, attn0, linw, linb, feat);
    k_lstm_gates<<<768, 256, 0, stream>>>(lwih, lwhh, lbih, lbhh, hx, feat, gates);
    k_lstm_cell<<<1, 768, 0, stream>>>(gates, cx, out, hxf);
    k_heads<<<1, 320, 0, stream>>>(hxf, temb, tx, cw, cb, aw, ab, out);
}

// Round 3
// 4323.023 us; speedup vs baseline: 4.9962x; 4.9962x over previous
//
#include <hip/hip_runtime.h>
#include <hip/hip_bf16.h>
#include <stdint.h>

// a3c_lstm_ga forward, MI355X. Float tensors are f32 (bf16-rounded values),
// ints int32. Output f32: [critic(1), actor(4), hx_new(768), cx_new(768)].
//
// Bug-faithful: only attn[0] is consumed -> one GRU scan (prev/next dead).
//
// GRU scan = serial floor: 2048 dependent 256->768 matvecs on ONE CU.
// R2 fix: W_hh row held in 32 NAMED uint4 vars (no local array -> no SROA
// failure) + __launch_bounds__(768,3) (VGPR cap 170, not 85). R1's wreg[128]
// landed in scratch (VGPR_Count=84) -> 21.6 ms.
// Upgrade: v_dot2_f32_f16 packed MACs (W f16 = exact for bf16-rounded data;
// h broadcast as hi/lo f16 split, residual ~2^-21). Guarded fallback: bf16
// unpack + fmaf.

typedef unsigned short bfraw;

#if __has_builtin(__builtin_amdgcn_fdot2)
#define USE_DOT2 1
typedef _Float16 half2v __attribute__((ext_vector_type(2)));
__device__ __forceinline__ float dot2(uint32_t w, uint32_t h, float acc) {
    return __builtin_amdgcn_fdot2(__builtin_bit_cast(half2v, w),
                                  __builtin_bit_cast(half2v, h), acc, false);
}
#else
#define USE_DOT2 0
#endif

__device__ __forceinline__ float bflo(uint32_t p) { return __uint_as_float(p << 16); }
__device__ __forceinline__ float bfhi(uint32_t p) { return __uint_as_float(p & 0xffff0000u); }
__device__ __forceinline__ float sigm(float x) { return 1.0f / (1.0f + __expf(-x)); }
__device__ __forceinline__ float tanh_f(float x) { return 2.0f / (1.0f + __expf(-2.0f * x)) - 1.0f; }
__device__ __forceinline__ uint32_t f2bf_rne(float f) {
    uint32_t u = __float_as_uint(f);
    return (u + 0x7fffu + ((u >> 16) & 1u)) >> 16;
}

// ---------------- pack W_hh f32 -> packed pairs (f16 for dot2, else bf16) ----
__global__ void k_pack(const float* __restrict__ whh, uint32_t* __restrict__ whhp) {
    int i = blockIdx.x * 256 + threadIdx.x;  // 98304 pairs
    if (i >= 98304) return;
#if USE_DOT2
    half2v p = {(_Float16)whh[2 * i], (_Float16)whh[2 * i + 1]};
    whhp[i] = __builtin_bit_cast(uint32_t, p);
#else
    whhp[i] = f2bf_rne(whh[2 * i]) | (f2bf_rne(whh[2 * i + 1]) << 16);
#endif
}

// ---------------- conv tower ----------------
__global__ void k_conv1(const float* __restrict__ x, const float* __restrict__ w,
                        const float* __restrict__ b, float* __restrict__ h1) {
    int idx = blockIdx.x * 256 + threadIdx.x;
    if (idx >= 128 * 30 * 30) return;
    int ox = idx % 30, oy = (idx / 30) % 30, oc = idx / 900;
    const float* wr = w + oc * 192;
    float acc = b[oc];
    for (int c = 0; c < 3; ++c)
        for (int ky = 0; ky < 8; ++ky) {
            const float* xr = x + (c * 124 + oy * 4 + ky) * 124 + ox * 4;
            const float* wk = wr + (c * 8 + ky) * 8;
#pragma unroll
            for (int kx = 0; kx < 8; ++kx) acc = fmaf(xr[kx], wk[kx], acc);
        }
    h1[idx] = fmaxf(acc, 0.0f);
}

__global__ void k_conv2(const float* __restrict__ h1, const float* __restrict__ w,
                        const float* __restrict__ b, float* __restrict__ h2) {
    int idx = blockIdx.x * 256 + threadIdx.x;
    if (idx >= 64 * 14 * 14) return;
    int ox = idx % 14, oy = (idx / 14) % 14, oc = idx / 196;
    float acc = b[oc];
    const float* wr = w + oc * 128 * 16;
    for (int c = 0; c < 128; ++c) {
#pragma unroll
        for (int ky = 0; ky < 4; ++ky) {
            const float* hr = h1 + (c * 30 + oy * 2 + ky) * 30 + ox * 2;
            const float* wk = wr + (c * 4 + ky) * 4;
#pragma unroll
            for (int kx = 0; kx < 4; ++kx) acc = fmaf(hr[kx], wk[kx], acc);
        }
    }
    h2[idx] = fmaxf(acc, 0.0f);
}

__global__ void k_conv3(const float* __restrict__ h2, const float* __restrict__ w,
                        const float* __restrict__ b, float* __restrict__ x3) {
    int idx = blockIdx.x * 256 + threadIdx.x;
    if (idx >= 64 * 6 * 6) return;
    int ox = idx % 6, oy = (idx / 6) % 6, oc = idx / 36;
    float acc = b[oc];
    const float* wr = w + oc * 64 * 16;
    for (int c = 0; c < 64; ++c) {
#pragma unroll
        for (int ky = 0; ky < 4; ++ky) {
            const float* hr = h2 + (c * 14 + oy * 2 + ky) * 14 + ox * 2;
            const float* wk = wr + (c * 4 + ky) * 4;
#pragma unroll
            for (int kx = 0; kx < 4; ++kx) acc = fmaf(hr[kx], wk[kx], acc);
        }
    }
    x3[idx] = fmaxf(acc, 0.0f);
}

// ---------------- GRU input-gate precompute (curr only) ----------------
__global__ void k_gi(const int* __restrict__ curr, const float* __restrict__ emb,
                     const float* __restrict__ wih, const float* __restrict__ bih,
                     float* __restrict__ gi) {
    int idx = blockIdx.x * 256 + threadIdx.x;  // 2048*768
    int j = idx % 768, t = idx / 768;
    int tok = curr[t];
    const float* e = emb + tok * 32;
    const float* wr = wih + j * 32;
    float acc = bih[j];
#pragma unroll
    for (int k = 0; k < 32; ++k) acc = fmaf(e[k], wr[k], acc);
    gi[idx] = acc;
}

// ---------------- GRU scan ----------------
#define REP32(X) X(0) X(1) X(2) X(3) X(4) X(5) X(6) X(7) X(8) X(9) X(10) X(11) \
    X(12) X(13) X(14) X(15) X(16) X(17) X(18) X(19) X(20) X(21) X(22) X(23)    \
    X(24) X(25) X(26) X(27) X(28) X(29) X(30) X(31)
#define DECLW(i) uint4 w##i;
#define LOADW(i) w##i = wp[i];

__global__ __launch_bounds__(768, 3) void k_gru_scan(
    const float* __restrict__ gi, const uint32_t* __restrict__ whhp,
    const float* __restrict__ bhh, const float* __restrict__ attn_w,
    const float* __restrict__ attn_b, float* __restrict__ attn0) {
    __shared__ float zs[256], gia[256], gha[256];
#if USE_DOT2
    __shared__ __align__(16) _Float16 hhi[256];
    __shared__ __align__(16) _Float16 hlo[256];
    const uint4* hhi4 = (const uint4*)hhi;
    const uint4* hlo4 = (const uint4*)hlo;
#else
    __shared__ __align__(16) float hs[256];
    const float4* hs4 = (const float4*)hs;
#endif
    const int t = threadIdx.x;

    // W_hh row t: 32 NAMED uint4 (128 VGPRs) — no array, no scratch demotion
    REP32(DECLW)
    {
        const uint4* wp = (const uint4*)(whhp + (size_t)t * 128);
        REP32(LOADW)
    }
    const float bh = bhh[t];
    float h_own = 0.0f;  // t<256: h[t] lives here in f32
    if (t < 256) {
#if USE_DOT2
        hhi[t] = (_Float16)0.0f;
        hlo[t] = (_Float16)0.0f;
#else
        hs[t] = 0.0f;
#endif
    }
    float giv = gi[t];
    __syncthreads();

#if USE_DOT2
#define DOTW(i)                            \
    {                                      \
        uint4 HI = hhi4[i];                \
        uint4 LO = hlo4[i];                \
        a0 = dot2(w##i.x, HI.x, a0);       \
        a1 = dot2(w##i.x, LO.x, a1);       \
        a2 = dot2(w##i.y, HI.y, a2);       \
        a3 = dot2(w##i.y, LO.y, a3);       \
        a0 = dot2(w##i.z, HI.z, a0);       \
        a1 = dot2(w##i.z, LO.z, a1);       \
        a2 = dot2(w##i.w, HI.w, a2);       \
        a3 = dot2(w##i.w, LO.w, a3);       \
    }
#else
#define DOTW(i)                                \
    {                                          \
        float4 hA = hs4[2 * i];                \
        float4 hB = hs4[2 * i + 1];            \
        a0 = fmaf(bflo(w##i.x), hA.x, a0);     \
        a1 = fmaf(bfhi(w##i.x), hA.y, a1);     \
        a2 = fmaf(bflo(w##i.y), hA.z, a2);     \
        a3 = fmaf(bfhi(w##i.y), hA.w, a3);     \
        a0 = fmaf(bflo(w##i.z), hB.x, a0);     \
        a1 = fmaf(bfhi(w##i.z), hB.y, a1);     \
        a2 = fmaf(bflo(w##i.w), hB.z, a2);     \
        a3 = fmaf(bfhi(w##i.w), hB.w, a3);     \
    }
#endif

    for (int step = 0; step < 2048; ++step) {
        float ginext = (step < 2047) ? gi[(size_t)(step + 1) * 768 + t] : 0.0f;

        float a0 = 0.f, a1 = 0.f, a2 = 0.f, a3 = 0.f;
        REP32(DOTW)
        const float hpart = bh + ((a0 + a1) + (a2 + a3));
        const float g = giv + hpart;

        float rv = sigm(g);         // r for t<256, z for t in [256,512)
        if (t >= 512) {             // n-rows publish i_n, h_n
            gia[t - 512] = giv;
            gha[t - 512] = hpart;
        } else if (t >= 256) {
            zs[t - 256] = rv;
        }
        __syncthreads();
        if (t < 256) {
            float n = tanh_f(fmaf(rv, gha[t], gia[t]));
            float z = zs[t];
            float hf = fmaf(z, h_own - n, n);  // (1-z)*n + z*h
            h_own = hf;
#if USE_DOT2
            _Float16 hi16 = (_Float16)hf;
            hhi[t] = hi16;
            hlo[t] = (_Float16)(hf - (float)hi16);
#else
            hs[t] = hf;
#endif
        }
        giv = ginext;
        __syncthreads();
    }

    // fused attention head: attn0[j] = sigm(attn_w[j] . h + attn_b[j]), j<64
    if (t < 64) {
        const float* ar = attn_w + t * 256;
        float acc = attn_b[t];
        for (int k = 0; k < 256; ++k) {
#if USE_DOT2
            float hk = (float)hhi[k] + (float)hlo[k];
#else
            float hk = hs[k];
#endif
            acc = fmaf(ar[k], hk, acc);
        }
        attn0[t] = sigm(acc);
    }
}

// ---------------- fuse + linear ----------------
__global__ void k_feat(const float* __restrict__ x3, const float* __restrict__ attn0,
                       const float* __restrict__ lw, const float* __restrict__ lb,
                       float* __restrict__ feat) {
    __shared__ __align__(16) float fused[2304];
    int t = threadIdx.x;  // 64
    for (int i = t; i < 2304; i += 64) fused[i] = x3[i] * attn0[i / 36];
    __syncthreads();
    int row = blockIdx.x * 64 + t;
    const float4* wv = (const float4*)(lw + (size_t)row * 2304);
    float acc = lb[row];
    for (int i = 0; i < 576; ++i) {
        float4 v = wv[i];
        const float* f = fused + i * 4;
        acc = fmaf(v.x, f[0], acc);
        acc = fmaf(v.y, f[1], acc);
        acc = fmaf(v.z, f[2], acc);
        acc = fmaf(v.w, f[3], acc);
    }
    feat[row] = fmaxf(acc, 0.0f);
}

// ---------------- LSTM gates ----------------
__global__ void k_lstm_gates(const float* __restrict__ wih, const float* __restrict__ whh,
                             const float* __restrict__ bih, const float* __restrict__ bhh,
                             const float* __restrict__ hx, const float* __restrict__ feat,
                             float* __restrict__ gates) {
    int wid = threadIdx.x >> 6, lane = threadIdx.x & 63;
    int row = blockIdx.x * 4 + wid;
    const float* wi = wih + (size_t)row * 768;
    const float* wh = whh + (size_t)row * 768;
    float acc = 0.0f;
#pragma unroll
    for (int i = 0; i < 12; ++i) {
        int k = lane + i * 64;
        acc = fmaf(wi[k], feat[k & 255], acc);
        acc = fmaf(wh[k], hx[k], acc);
    }
#pragma unroll
    for (int s = 32; s; s >>= 1) acc += __shfl_down(acc, s, 64);
    if (lane == 0) gates[row] = acc + bih[row] + bhh[row];
}

// ---------------- LSTM cell ----------------
__global__ void k_lstm_cell(const float* __restrict__ gates, const float* __restrict__ cx,
                            float* __restrict__ out, float* __restrict__ hxf) {
    int i = threadIdx.x;  // 768
    float g_i = gates[i], g_f = gates[768 + i], g_g = gates[1536 + i], g_o = gates[2304 + i];
    float c = cx[i];
    float cn = sigm(g_f) * c + sigm(g_i) * tanh_f(g_g);
    float hn = sigm(g_o) * tanh_f(cn);
    out[5 + i] = hn;
    out[5 + 768 + i] = cn;
    hxf[i] = hn;
}

// ---------------- heads ----------------
__global__ void k_heads(const float* __restrict__ hxf, const float* __restrict__ temb,
                        const int* __restrict__ tx, const float* __restrict__ cw,
                        const float* __restrict__ cb, const float* __restrict__ aw,
                        const float* __restrict__ ab, float* __restrict__ out) {
    __shared__ float z[800];
    int t = threadIdx.x;  // 320
    for (int i = t; i < 768; i += 320) z[i] = hxf[i];
    if (t < 32) z[768 + t] = temb[tx[0] * 32 + t];
    __syncthreads();
    int w = t >> 6, lane = t & 63;
    const float* row = (w == 0) ? cw : (aw + (size_t)(w - 1) * 800);
    float acc = 0.0f;
    for (int k = lane; k < 800; k += 64) acc = fmaf(row[k], z[k], acc);
#pragma unroll
    for (int s = 32; s; s >>= 1) acc += __shfl_down(acc, s, 64);
    if (lane == 0) {
        float b = (w == 0) ? cb[0] : ab[w - 1];
        out[w] = acc + b;
    }
}

extern "C" void kernel_launch(void* const* d_in, const int* in_sizes, int n_in,
                              void* d_out, int out_size, void* d_ws, size_t ws_size,
                              hipStream_t stream) {
    const float* x = (const float*)d_in[0];
    const int* curr = (const int*)d_in[1];
    const int* tx = (const int*)d_in[4];
    const float* hx = (const float*)d_in[5];
    const float* cx = (const float*)d_in[6];
    const float* c1w = (const float*)d_in[7];
    const float* c1b = (const float*)d_in[8];
    const float* c2w = (const float*)d_in[9];
    const float* c2b = (const float*)d_in[10];
    const float* c3w = (const float*)d_in[11];
    const float* c3b = (const float*)d_in[12];
    const float* emb = (const float*)d_in[13];
    const float* temb = (const float*)d_in[14];
    const float* gwih = (const float*)d_in[15];
    const float* gwhh = (const float*)d_in[16];
    const float* gbih = (const float*)d_in[17];
    const float* gbhh = (const float*)d_in[18];
    const float* attw = (const float*)d_in[19];
    const float* attb = (const float*)d_in[20];
    const float* linw = (const float*)d_in[21];
    const float* linb = (const float*)d_in[22];
    const float* lwih = (const float*)d_in[23];
    const float* lwhh = (const float*)d_in[24];
    const float* lbih = (const float*)d_in[25];
    const float* lbhh = (const float*)d_in[26];
    const float* cw = (const float*)d_in[27];
    const float* cb = (const float*)d_in[28];
    const float* aw = (const float*)d_in[29];
    const float* ab = (const float*)d_in[30];
    float* out = (float*)d_out;

    char* ws = (char*)d_ws;
    float* gi = (float*)(ws + 0);                // 2048*768 f32
    float* h1 = (float*)(ws + 6291456);
    float* h2 = (float*)(ws + 6752256);
    float* x3 = (float*)(ws + 6802432);
    float* attn0 = (float*)(ws + 6811648);
    float* feat = (float*)(ws + 6811904);
    float* gates = (float*)(ws + 6812928);
    float* hxf = (float*)(ws + 6825216);
    uint32_t* whhp = (uint32_t*)(ws + 6828288);  // 98304 u32

    k_pack<<<384, 256, 0, stream>>>(gwhh, whhp);
    k_gi<<<6144, 256, 0, stream>>>(curr, emb, gwih, gbih, gi);
    k_conv1<<<450, 256, 0, stream>>>(x, c1w, c1b, h1);
    k_conv2<<<49, 256, 0, stream>>>(h1, c2w, c2b, h2);
    k_conv3<<<9, 256, 0, stream>>>(h2, c3w, c3b, x3);
    k_gru_scan<<<1, 768, 0, stream>>>(gi, whhp, gbhh, attw, attb, attn0);
    k_feat<<<4, 64, 0, stream>>>(x3, attn0, linw, linb, feat);
    k_lstm_gates<<<768, 256, 0, stream>>>(lwih, lwhh, lbih, lbhh, hx, feat, gates);
    k_lstm_cell<<<1, 768, 0, stream>>>(gates, cx, out, hxf);
    k_heads<<<1, 320, 0, stream>>>(hxf, temb, tx, cw, cb, aw, ab, out);
}

// Round 4
// 4284.562 us; speedup vs baseline: 5.0411x; 1.0090x over previous
//
#include <hip/hip_runtime.h>
#include <hip/hip_bf16.h>
#include <stdint.h>

// a3c_lstm_ga forward, MI355X. Float tensors f32 (bf16-rounded values), ints
// int32. Output f32: [critic(1), actor(4), hx_new(768), cx_new(768)].
//
// Bug-faithful: only attn[0] is consumed -> one GRU scan (prev/next dead).
//
// GRU scan = serial floor: 2048 dependent 256->768 matvecs on ONE CU.
// R3 result: named uint4 vars STILL re-loaded from L2 every step (VGPR=84) --
// with no global stores in the loop the loads are loop-invariant and LLVM
// sinks them back in rather than hold 128 live VGPRs. R4 fix: launder the
// loaded values through asm volatile("":"+v") so they cannot be
// rematerialized, + amdgpu_waves_per_eu(3,3) so the allocator budget is 168
// VGPRs (grid = 1 block = 12 waves = 3/EU exactly; max=3 costs nothing).

typedef unsigned short bfraw;

#if __has_builtin(__builtin_amdgcn_fdot2)
#define USE_DOT2 1
typedef _Float16 half2v __attribute__((ext_vector_type(2)));
__device__ __forceinline__ float dot2(uint32_t w, uint32_t h, float acc) {
    return __builtin_amdgcn_fdot2(__builtin_bit_cast(half2v, w),
                                  __builtin_bit_cast(half2v, h), acc, false);
}
#else
#define USE_DOT2 0
#endif

__device__ __forceinline__ float bflo(uint32_t p) { return __uint_as_float(p << 16); }
__device__ __forceinline__ float bfhi(uint32_t p) { return __uint_as_float(p & 0xffff0000u); }
__device__ __forceinline__ float sigm(float x) { return 1.0f / (1.0f + __expf(-x)); }
__device__ __forceinline__ float tanh_f(float x) { return 2.0f / (1.0f + __expf(-2.0f * x)) - 1.0f; }
__device__ __forceinline__ uint32_t f2bf_rne(float f) {
    uint32_t u = __float_as_uint(f);
    return (u + 0x7fffu + ((u >> 16) & 1u)) >> 16;
}

// ---------------- pack W_hh f32 -> packed pairs (f16 for dot2, else bf16) ----
__global__ void k_pack(const float* __restrict__ whh, uint32_t* __restrict__ whhp) {
    int i = blockIdx.x * 256 + threadIdx.x;  // 98304 pairs
    if (i >= 98304) return;
#if USE_DOT2
    half2v p = {(_Float16)whh[2 * i], (_Float16)whh[2 * i + 1]};
    whhp[i] = __builtin_bit_cast(uint32_t, p);
#else
    whhp[i] = f2bf_rne(whh[2 * i]) | (f2bf_rne(whh[2 * i + 1]) << 16);
#endif
}

// ---------------- conv tower ----------------
__global__ void k_conv1(const float* __restrict__ x, const float* __restrict__ w,
                        const float* __restrict__ b, float* __restrict__ h1) {
    int idx = blockIdx.x * 256 + threadIdx.x;
    if (idx >= 128 * 30 * 30) return;
    int ox = idx % 30, oy = (idx / 30) % 30, oc = idx / 900;
    const float* wr = w + oc * 192;
    float acc = b[oc];
    for (int c = 0; c < 3; ++c)
        for (int ky = 0; ky < 8; ++ky) {
            const float* xr = x + (c * 124 + oy * 4 + ky) * 124 + ox * 4;
            const float* wk = wr + (c * 8 + ky) * 8;
#pragma unroll
            for (int kx = 0; kx < 8; ++kx) acc = fmaf(xr[kx], wk[kx], acc);
        }
    h1[idx] = fmaxf(acc, 0.0f);
}

__global__ void k_conv2(const float* __restrict__ h1, const float* __restrict__ w,
                        const float* __restrict__ b, float* __restrict__ h2) {
    int idx = blockIdx.x * 256 + threadIdx.x;
    if (idx >= 64 * 14 * 14) return;
    int ox = idx % 14, oy = (idx / 14) % 14, oc = idx / 196;
    float acc = b[oc];
    const float* wr = w + oc * 128 * 16;
    for (int c = 0; c < 128; ++c) {
#pragma unroll
        for (int ky = 0; ky < 4; ++ky) {
            const float* hr = h1 + (c * 30 + oy * 2 + ky) * 30 + ox * 2;
            const float* wk = wr + (c * 4 + ky) * 4;
#pragma unroll
            for (int kx = 0; kx < 4; ++kx) acc = fmaf(hr[kx], wk[kx], acc);
        }
    }
    h2[idx] = fmaxf(acc, 0.0f);
}

__global__ void k_conv3(const float* __restrict__ h2, const float* __restrict__ w,
                        const float* __restrict__ b, float* __restrict__ x3) {
    int idx = blockIdx.x * 256 + threadIdx.x;
    if (idx >= 64 * 6 * 6) return;
    int ox = idx % 6, oy = (idx / 6) % 6, oc = idx / 36;
    float acc = b[oc];
    const float* wr = w + oc * 64 * 16;
    for (int c = 0; c < 64; ++c) {
#pragma unroll
        for (int ky = 0; ky < 4; ++ky) {
            const float* hr = h2 + (c * 14 + oy * 2 + ky) * 14 + ox * 2;
            const float* wk = wr + (c * 4 + ky) * 4;
#pragma unroll
            for (int kx = 0; kx < 4; ++kx) acc = fmaf(hr[kx], wk[kx], acc);
        }
    }
    x3[idx] = fmaxf(acc, 0.0f);
}

// ---------------- GRU input-gate precompute (curr only), float4-vectorized ----
__global__ void k_gi(const int* __restrict__ curr, const float* __restrict__ emb,
                     const float* __restrict__ wih, const float* __restrict__ bih,
                     float* __restrict__ gi) {
    int idx = blockIdx.x * 256 + threadIdx.x;  // 2048*768
    int j = idx % 768, t = idx / 768;
    int tok = curr[t];
    const float4* e = (const float4*)(emb + tok * 32);
    const float4* wr = (const float4*)(wih + j * 32);
    float acc = bih[j];
#pragma unroll
    for (int k = 0; k < 8; ++k) {
        float4 ev = e[k], wv = wr[k];
        acc = fmaf(ev.x, wv.x, acc);
        acc = fmaf(ev.y, wv.y, acc);
        acc = fmaf(ev.z, wv.z, acc);
        acc = fmaf(ev.w, wv.w, acc);
    }
    gi[idx] = acc;
}

// ---------------- GRU scan ----------------
#define REP32(X) X(0) X(1) X(2) X(3) X(4) X(5) X(6) X(7) X(8) X(9) X(10) X(11) \
    X(12) X(13) X(14) X(15) X(16) X(17) X(18) X(19) X(20) X(21) X(22) X(23)    \
    X(24) X(25) X(26) X(27) X(28) X(29) X(30) X(31)
#define DECLW(i) uint4 w##i;
#define LOADW(i) w##i = wp[i];
// Launder loaded values: asm-defined outputs cannot be rematerialized by
// re-loading, so they must stay live in VGPRs for the whole loop.
#define TIEW(i) asm volatile("" : "+v"(w##i.x), "+v"(w##i.y), "+v"(w##i.z), "+v"(w##i.w));

__global__ __launch_bounds__(768) __attribute__((amdgpu_waves_per_eu(3, 3)))
void k_gru_scan(
    const float* __restrict__ gi, const uint32_t* __restrict__ whhp,
    const float* __restrict__ bhh, const float* __restrict__ attn_w,
    const float* __restrict__ attn_b, float* __restrict__ attn0) {
    __shared__ float zs[256], gia[256], gha[256];
#if USE_DOT2
    __shared__ __align__(16) _Float16 hhi[256];
    __shared__ __align__(16) _Float16 hlo[256];
    const uint4* hhi4 = (const uint4*)hhi;
    const uint4* hlo4 = (const uint4*)hlo;
#else
    __shared__ __align__(16) float hs[256];
    const float4* hs4 = (const float4*)hs;
#endif
    const int t = threadIdx.x;

    // W_hh row t: 32 named uint4 (128 VGPRs), laundered -> register-resident
    REP32(DECLW)
    {
        const uint4* wp = (const uint4*)(whhp + (size_t)t * 128);
        REP32(LOADW)
    }
    REP32(TIEW)
    const float bh = bhh[t];
    float h_own = 0.0f;  // t<256: h[t] lives here in f32
    if (t < 256) {
#if USE_DOT2
        hhi[t] = (_Float16)0.0f;
        hlo[t] = (_Float16)0.0f;
#else
        hs[t] = 0.0f;
#endif
    }
    float giv = gi[t];
    __syncthreads();

#if USE_DOT2
#define DOTW(i)                      \
    {                                \
        uint4 HI = hhi4[i];          \
        uint4 LO = hlo4[i];          \
        a0 = dot2(w##i.x, HI.x, a0); \
        a1 = dot2(w##i.x, LO.x, a1); \
        a2 = dot2(w##i.y, HI.y, a2); \
        a3 = dot2(w##i.y, LO.y, a3); \
        a0 = dot2(w##i.z, HI.z, a0); \
        a1 = dot2(w##i.z, LO.z, a1); \
        a2 = dot2(w##i.w, HI.w, a2); \
        a3 = dot2(w##i.w, LO.w, a3); \
    }
#else
#define DOTW(i)                            \
    {                                      \
        float4 hA = hs4[2 * i];            \
        float4 hB = hs4[2 * i + 1];        \
        a0 = fmaf(bflo(w##i.x), hA.x, a0); \
        a1 = fmaf(bfhi(w##i.x), hA.y, a1); \
        a2 = fmaf(bflo(w##i.y), hA.z, a2); \
        a3 = fmaf(bfhi(w##i.y), hA.w, a3); \
        a0 = fmaf(bflo(w##i.z), hB.x, a0); \
        a1 = fmaf(bfhi(w##i.z), hB.y, a1); \
        a2 = fmaf(bflo(w##i.w), hB.z, a2); \
        a3 = fmaf(bfhi(w##i.w), hB.w, a3); \
    }
#endif

    for (int step = 0; step < 2048; ++step) {
        float ginext = (step < 2047) ? gi[(size_t)(step + 1) * 768 + t] : 0.0f;

        float a0 = 0.f, a1 = 0.f, a2 = 0.f, a3 = 0.f;
        REP32(DOTW)
        const float hpart = bh + ((a0 + a1) + (a2 + a3));
        const float g = giv + hpart;

        float rv = sigm(g);  // r for t<256, z for t in [256,512)
        if (t >= 512) {      // n-rows publish i_n, h_n
            gia[t - 512] = giv;
            gha[t - 512] = hpart;
        } else if (t >= 256) {
            zs[t - 256] = rv;
        }
        __syncthreads();
        if (t < 256) {
            float n = tanh_f(fmaf(rv, gha[t], gia[t]));
            float z = zs[t];
            float hf = fmaf(z, h_own - n, n);  // (1-z)*n + z*h
            h_own = hf;
#if USE_DOT2
            _Float16 hi16 = (_Float16)hf;
            hhi[t] = hi16;
            hlo[t] = (_Float16)(hf - (float)hi16);
#else
            hs[t] = hf;
#endif
        }
        giv = ginext;
        __syncthreads();
    }

    // fused attention head: attn0[j] = sigm(attn_w[j] . h + attn_b[j]), j<64
    if (t < 64) {
        const float* ar = attn_w + t * 256;
        float acc = attn_b[t];
        for (int k = 0; k < 256; ++k) {
#if USE_DOT2
            float hk = (float)hhi[k] + (float)hlo[k];
#else
            float hk = hs[k];
#endif
            acc = fmaf(ar[k], hk, acc);
        }
        attn0[t] = sigm(acc);
    }
}

// ---------------- fuse + linear ----------------
__global__ void k_feat(const float* __restrict__ x3, const float* __restrict__ attn0,
                       const float* __restrict__ lw, const float* __restrict__ lb,
                       float* __restrict__ feat) {
    __shared__ __align__(16) float fused[2304];
    int t = threadIdx.x;  // 64
    for (int i = t; i < 2304; i += 64) fused[i] = x3[i] * attn0[i / 36];
    __syncthreads();
    int row = blockIdx.x * 64 + t;
    const float4* wv = (const float4*)(lw + (size_t)row * 2304);
    float acc = lb[row];
    for (int i = 0; i < 576; ++i) {
        float4 v = wv[i];
        const float* f = fused + i * 4;
        acc = fmaf(v.x, f[0], acc);
        acc = fmaf(v.y, f[1], acc);
        acc = fmaf(v.z, f[2], acc);
        acc = fmaf(v.w, f[3], acc);
    }
    feat[row] = fmaxf(acc, 0.0f);
}

// ---------------- LSTM gates ----------------
__global__ void k_lstm_gates(const float* __restrict__ wih, const float* __restrict__ whh,
                             const float* __restrict__ bih, const float* __restrict__ bhh,
                             const float* __restrict__ hx, const float* __restrict__ feat,
                             float* __restrict__ gates) {
    int wid = threadIdx.x >> 6, lane = threadIdx.x & 63;
    int row = blockIdx.x * 4 + wid;
    const float* wi = wih + (size_t)row * 768;
    const float* wh = whh + (size_t)row * 768;
    float acc = 0.0f;
#pragma unroll
    for (int i = 0; i < 12; ++i) {
        int k = lane + i * 64;
        acc = fmaf(wi[k], feat[k & 255], acc);
        acc = fmaf(wh[k], hx[k], acc);
    }
#pragma unroll
    for (int s = 32; s; s >>= 1) acc += __shfl_down(acc, s, 64);
    if (lane == 0) gates[row] = acc + bih[row] + bhh[row];
}

// ---------------- LSTM cell ----------------
__global__ void k_lstm_cell(const float* __restrict__ gates, const float* __restrict__ cx,
                            float* __restrict__ out, float* __restrict__ hxf) {
    int i = threadIdx.x;  // 768
    float g_i = gates[i], g_f = gates[768 + i], g_g = gates[1536 + i], g_o = gates[2304 + i];
    float c = cx[i];
    float cn = sigm(g_f) * c + sigm(g_i) * tanh_f(g_g);
    float hn = sigm(g_o) * tanh_f(cn);
    out[5 + i] = hn;
    out[5 + 768 + i] = cn;
    hxf[i] = hn;
}

// ---------------- heads ----------------
__global__ void k_heads(const float* __restrict__ hxf, const float* __restrict__ temb,
                        const int* __restrict__ tx, const float* __restrict__ cw,
                        const float* __restrict__ cb, const float* __restrict__ aw,
                        const float* __restrict__ ab, float* __restrict__ out) {
    __shared__ float z[800];
    int t = threadIdx.x;  // 320
    for (int i = t; i < 768; i += 320) z[i] = hxf[i];
    if (t < 32) z[768 + t] = temb[tx[0] * 32 + t];
    __syncthreads();
    int w = t >> 6, lane = t & 63;
    const float* row = (w == 0) ? cw : (aw + (size_t)(w - 1) * 800);
    float acc = 0.0f;
    for (int k = lane; k < 800; k += 64) acc = fmaf(row[k], z[k], acc);
#pragma unroll
    for (int s = 32; s; s >>= 1) acc += __shfl_down(acc, s, 64);
    if (lane == 0) {
        float b = (w == 0) ? cb[0] : ab[w - 1];
        out[w] = acc + b;
    }
}

extern "C" void kernel_launch(void* const* d_in, const int* in_sizes, int n_in,
                              void* d_out, int out_size, void* d_ws, size_t ws_size,
                              hipStream_t stream) {
    const float* x = (const float*)d_in[0];
    const int* curr = (const int*)d_in[1];
    const int* tx = (const int*)d_in[4];
    const float* hx = (const float*)d_in[5];
    const float* cx = (const float*)d_in[6];
    const float* c1w = (const float*)d_in[7];
    const float* c1b = (const float*)d_in[8];
    const float* c2w = (const float*)d_in[9];
    const float* c2b = (const float*)d_in[10];
    const float* c3w = (const float*)d_in[11];
    const float* c3b = (const float*)d_in[12];
    const float* emb = (const float*)d_in[13];
    const float* temb = (const float*)d_in[14];
    const float* gwih = (const float*)d_in[15];
    const float* gwhh = (const float*)d_in[16];
    const float* gbih = (const float*)d_in[17];
    const float* gbhh = (const float*)d_in[18];
    const float* attw = (const float*)d_in[19];
    const float* attb = (const float*)d_in[20];
    const float* linw = (const float*)d_in[21];
    const float* linb = (const float*)d_in[22];
    const float* lwih = (const float*)d_in[23];
    const float* lwhh = (const float*)d_in[24];
    const float* lbih = (const float*)d_in[25];
    const float* lbhh = (const float*)d_in[26];
    const float* cw = (const float*)d_in[27];
    const float* cb = (const float*)d_in[28];
    const float* aw = (const float*)d_in[29];
    const float* ab = (const float*)d_in[30];
    float* out = (float*)d_out;

    char* ws = (char*)d_ws;
    float* gi = (float*)(ws + 0);                // 2048*768 f32
    float* h1 = (float*)(ws + 6291456);
    float* h2 = (float*)(ws + 6752256);
    float* x3 = (float*)(ws + 6802432);
    float* attn0 = (float*)(ws + 6811648);
    float* feat = (float*)(ws + 6811904);
    float* gates = (float*)(ws + 6812928);
    float* hxf = (float*)(ws + 6825216);
    uint32_t* whhp = (uint32_t*)(ws + 6828288);  // 98304 u32

    k_pack<<<384, 256, 0, stream>>>(gwhh, whhp);
    k_gi<<<6144, 256, 0, stream>>>(curr, emb, gwih, gbih, gi);
    k_conv1<<<450, 256, 0, stream>>>(x, c1w, c1b, h1);
    k_conv2<<<49, 256, 0, stream>>>(h1, c2w, c2b, h2);
    k_conv3<<<9, 256, 0, stream>>>(h2, c3w, c3b, x3);
    k_gru_scan<<<1, 768, 0, stream>>>(gi, whhp, gbhh, attw, attb, attn0);
    k_feat<<<4, 64, 0, stream>>>(x3, attn0, linw, linb, feat);
    k_lstm_gates<<<768, 256, 0, stream>>>(lwih, lwhh, lbih, lbhh, hx, feat, gates);
    k_lstm_cell<<<1, 768, 0, stream>>>(gates, cx, out, hxf);
    k_heads<<<1, 320, 0, stream>>>(hxf, temb, tx, cw, cb, aw, ab, out);
}

// Round 5
// 3421.824 us; speedup vs baseline: 6.3121x; 1.2521x over previous
//
#include <hip/hip_runtime.h>
#include <hip/hip_bf16.h>
#include <stdint.h>

// a3c_lstm_ga forward, MI355X. Float tensors f32 (bf16-rounded values), ints
// int32. Output f32: [critic(1), actor(4), hx_new(768), cx_new(768)].
// Bug-faithful: only attn[0] consumed -> one GRU scan.
//
// R5: GRU scan moved to the MFMA pipe. 256 thr / 4 waves / waves_per_eu(1,1)
// (512-reg budget). Wave w owns rows [w*192, w*192+192) = 12 N-tiles; W_hh
// (f16, exact for bf16-rounded data) lives in 96 laundered uint4 B-frags
// (384 regs/wave, unified VGPR/AGPR file). h enters MFMA as A rows 0/1:
// row0 = h_hi (f16), row1 = (h - h_hi)*1024 (scaled past f16 subnormals);
// y = D[0][n] + D[1][n]/1024. 96 mfma_16x16x32_f16 per wave per step.

typedef _Float16 half8 __attribute__((ext_vector_type(8)));
typedef _Float16 half2v __attribute__((ext_vector_type(2)));
typedef float f32x4 __attribute__((ext_vector_type(4)));

__device__ __forceinline__ float sigm(float x) { return 1.0f / (1.0f + __expf(-x)); }
__device__ __forceinline__ float tanh_f(float x) { return 2.0f / (1.0f + __expf(-2.0f * x)) - 1.0f; }

// ---------------- pack W_hh f32 -> f16 pairs ----------------
__global__ void k_pack(const float* __restrict__ whh, uint32_t* __restrict__ wf16p) {
    int i = blockIdx.x * 256 + threadIdx.x;  // 98304 pairs
    if (i >= 98304) return;
    half2v p = {(_Float16)whh[2 * i], (_Float16)whh[2 * i + 1]};
    wf16p[i] = __builtin_bit_cast(uint32_t, p);
}

// ---------------- conv tower ----------------
__global__ void k_conv1(const float* __restrict__ x, const float* __restrict__ w,
                        const float* __restrict__ b, float* __restrict__ h1) {
    int idx = blockIdx.x * 256 + threadIdx.x;
    if (idx >= 128 * 30 * 30) return;
    int ox = idx % 30, oy = (idx / 30) % 30, oc = idx / 900;
    const float* wr = w + oc * 192;
    float acc = b[oc];
    for (int c = 0; c < 3; ++c)
        for (int ky = 0; ky < 8; ++ky) {
            const float* xr = x + (c * 124 + oy * 4 + ky) * 124 + ox * 4;
            const float* wk = wr + (c * 8 + ky) * 8;
#pragma unroll
            for (int kx = 0; kx < 8; ++kx) acc = fmaf(xr[kx], wk[kx], acc);
        }
    h1[idx] = fmaxf(acc, 0.0f);
}

__global__ void k_conv2(const float* __restrict__ h1, const float* __restrict__ w,
                        const float* __restrict__ b, float* __restrict__ h2) {
    int idx = blockIdx.x * 256 + threadIdx.x;
    if (idx >= 64 * 14 * 14) return;
    int ox = idx % 14, oy = (idx / 14) % 14, oc = idx / 196;
    float acc = b[oc];
    const float* wr = w + oc * 128 * 16;
    for (int c = 0; c < 128; ++c) {
#pragma unroll
        for (int ky = 0; ky < 4; ++ky) {
            const float* hr = h1 + (c * 30 + oy * 2 + ky) * 30 + ox * 2;
            const float* wk = wr + (c * 4 + ky) * 4;
#pragma unroll
            for (int kx = 0; kx < 4; ++kx) acc = fmaf(hr[kx], wk[kx], acc);
        }
    }
    h2[idx] = fmaxf(acc, 0.0f);
}

__global__ void k_conv3(const float* __restrict__ h2, const float* __restrict__ w,
                        const float* __restrict__ b, float* __restrict__ x3) {
    int idx = blockIdx.x * 256 + threadIdx.x;
    if (idx >= 64 * 6 * 6) return;
    int ox = idx % 6, oy = (idx / 6) % 6, oc = idx / 36;
    float acc = b[oc];
    const float* wr = w + oc * 64 * 16;
    for (int c = 0; c < 64; ++c) {
#pragma unroll
        for (int ky = 0; ky < 4; ++ky) {
            const float* hr = h2 + (c * 14 + oy * 2 + ky) * 14 + ox * 2;
            const float* wk = wr + (c * 4 + ky) * 4;
#pragma unroll
            for (int kx = 0; kx < 4; ++kx) acc = fmaf(hr[kx], wk[kx], acc);
        }
    }
    x3[idx] = fmaxf(acc, 0.0f);
}

// ---------------- GRU input-gate precompute ----------------
__global__ void k_gi(const int* __restrict__ curr, const float* __restrict__ emb,
                     const float* __restrict__ wih, const float* __restrict__ bih,
                     float* __restrict__ gi) {
    int idx = blockIdx.x * 256 + threadIdx.x;  // 2048*768
    int j = idx % 768, t = idx / 768;
    int tok = curr[t];
    const float4* e = (const float4*)(emb + tok * 32);
    const float4* wr = (const float4*)(wih + j * 32);
    float acc = bih[j];
#pragma unroll
    for (int k = 0; k < 8; ++k) {
        float4 ev = e[k], wv = wr[k];
        acc = fmaf(ev.x, wv.x, acc);
        acc = fmaf(ev.y, wv.y, acc);
        acc = fmaf(ev.z, wv.z, acc);
        acc = fmaf(ev.w, wv.w, acc);
    }
    gi[idx] = acc;
}

// ---------------- MFMA GRU scan ----------------
#define FOR8(X, nt) X(nt, 0) X(nt, 1) X(nt, 2) X(nt, 3) X(nt, 4) X(nt, 5) X(nt, 6) X(nt, 7)
#define FOR12(Y) Y(0) Y(1) Y(2) Y(3) Y(4) Y(5) Y(6) Y(7) Y(8) Y(9) Y(10) Y(11)

#define DECLB(nt, kt) uint4 b##nt##_##kt;
#define DECLBROW(nt) FOR8(DECLB, nt)
#define LOADB(nt, kt) b##nt##_##kt = wp4[nt * 512 + kt * 4 + quad];
#define LOADBROW(nt) FOR8(LOADB, nt)
#define TIEB(nt, kt) \
    asm volatile("" : "+v"(b##nt##_##kt.x), "+v"(b##nt##_##kt.y), "+v"(b##nt##_##kt.z), "+v"(b##nt##_##kt.w));
#define TIEBROW(nt) FOR8(TIEB, nt)
#define DECLBIAS(nt) const float bias##nt = bhh[wbase + nt * 16 + n16];
#define DECLACC(nt) f32x4 acc##nt;
#define ZEROACC(nt) acc##nt = (f32x4)(0.0f);
#define MF(nt, kt) \
    acc##nt = __builtin_amdgcn_mfma_f32_16x16x32_f16(a##kt, __builtin_bit_cast(half8, b##nt##_##kt), acc##nt, 0, 0, 0);
#define MFK(kt) MF(0, kt) MF(1, kt) MF(2, kt) MF(3, kt) MF(4, kt) MF(5, kt) \
                MF(6, kt) MF(7, kt) MF(8, kt) MF(9, kt) MF(10, kt) MF(11, kt)
#define LOADA(kt) half8 a##kt = __builtin_bit_cast(half8, abase[kt * 4 + quad]);
#define EPI(nt)                                                                   \
    if (lane < 16) gh[wbase + nt * 16 + lane] = acc##nt.x + acc##nt.y * 0.0009765625f + bias##nt;

__global__ __attribute__((amdgpu_flat_work_group_size(256, 256), amdgpu_waves_per_eu(1, 1)))
void k_gru_scan(const float* __restrict__ gi, const uint32_t* __restrict__ wf16p,
                const float* __restrict__ bhh, const float* __restrict__ attn_w,
                const float* __restrict__ attn_b, float* __restrict__ attn0) {
    __shared__ __align__(16) _Float16 hhi[256];
    __shared__ __align__(16) _Float16 hlo[256];  // (h - hhi) * 1024
    __shared__ float gh[768];
    const int tid = threadIdx.x;   // 0..255
    const int lane = tid & 63;
    const int wv = tid >> 6;       // wave 0..3
    const int n16 = lane & 15;     // B col = output row-in-tile; also A row m
    const int quad = lane >> 4;    // k-subchunk selector
    const int wbase = wv * 192;    // this wave's first output row

    // B-fragments: lane holds W[wbase + nt*16 + n16][kt*32 + quad*8 + j], j=0..7
    FOR12(DECLBROW)
    {
        const uint4* wp4 = (const uint4*)(wf16p + (size_t)(wbase + n16) * 128);
        FOR12(LOADBROW)
    }
    FOR12(TIEBROW)  // launder: cannot be rematerialized by re-loading
    FOR12(DECLBIAS)
    FOR12(DECLACC)

    float h_own = 0.0f;  // thread tid owns h[tid]
    hhi[tid] = (_Float16)0.0f;
    hlo[tid] = (_Float16)0.0f;
    float gv0 = gi[tid], gv1 = gi[256 + tid], gv2 = gi[512 + tid];
    __syncthreads();

    const uint4* abase = (n16 == 1) ? (const uint4*)hlo : (const uint4*)hhi;

#pragma clang loop unroll(disable)
    for (int step = 0; step < 2048; ++step) {
        // A-fragments from LDS (row0=hhi, row1=hlo, rows>=2 harmless garbage)
        LOADA(0) LOADA(1) LOADA(2) LOADA(3) LOADA(4) LOADA(5) LOADA(6) LOADA(7)

        // prefetch next step's input gates; latency hides under MFMAs
        float gn0 = 0.f, gn1 = 0.f, gn2 = 0.f;
        if (step < 2047) {
            const float* gp = gi + (size_t)(step + 1) * 768 + tid;
            gn0 = gp[0]; gn1 = gp[256]; gn2 = gp[512];
        }

        FOR12(ZEROACC)
        MFK(0) MFK(1) MFK(2) MFK(3) MFK(4) MFK(5) MFK(6) MFK(7)

        // y[wbase+nt*16+col] = D[0][col] + D[1][col]/1024 + bhh  (lanes 0-15)
        FOR12(EPI)
        __syncthreads();

        // gate math: thread tid handles element tid
        float r = sigm(gv0 + gh[tid]);
        float z = sigm(gv1 + gh[256 + tid]);
        float n = tanh_f(fmaf(r, gh[512 + tid], gv2));
        h_own = fmaf(z, h_own - n, n);  // (1-z)*n + z*h
        _Float16 hi16 = (_Float16)h_own;
        hhi[tid] = hi16;
        hlo[tid] = (_Float16)((h_own - (float)hi16) * 1024.0f);
        gv0 = gn0; gv1 = gn1; gv2 = gn2;
        __syncthreads();
    }

    // fused attention head: attn0[j] = sigm(attn_w[j] . h + attn_b[j]), j<64
    if (tid < 64) {
        const float* ar = attn_w + tid * 256;
        float acc = attn_b[tid];
        for (int k = 0; k < 256; ++k) {
            float hk = (float)hhi[k] + (float)hlo[k] * 0.0009765625f;
            acc = fmaf(ar[k], hk, acc);
        }
        attn0[tid] = sigm(acc);
    }
}

// ---------------- fuse + linear ----------------
__global__ void k_feat(const float* __restrict__ x3, const float* __restrict__ attn0,
                       const float* __restrict__ lw, const float* __restrict__ lb,
                       float* __restrict__ feat) {
    __shared__ __align__(16) float fused[2304];
    int t = threadIdx.x;  // 64
    for (int i = t; i < 2304; i += 64) fused[i] = x3[i] * attn0[i / 36];
    __syncthreads();
    int row = blockIdx.x * 64 + t;
    const float4* wvv = (const float4*)(lw + (size_t)row * 2304);
    float acc = lb[row];
    for (int i = 0; i < 576; ++i) {
        float4 v = wvv[i];
        const float* f = fused + i * 4;
        acc = fmaf(v.x, f[0], acc);
        acc = fmaf(v.y, f[1], acc);
        acc = fmaf(v.z, f[2], acc);
        acc = fmaf(v.w, f[3], acc);
    }
    feat[row] = fmaxf(acc, 0.0f);
}

// ---------------- LSTM gates ----------------
__global__ void k_lstm_gates(const float* __restrict__ wih, const float* __restrict__ whh,
                             const float* __restrict__ bih, const float* __restrict__ bhh,
                             const float* __restrict__ hx, const float* __restrict__ feat,
                             float* __restrict__ gates) {
    int wid = threadIdx.x >> 6, lane = threadIdx.x & 63;
    int row = blockIdx.x * 4 + wid;
    const float* wi = wih + (size_t)row * 768;
    const float* wh = whh + (size_t)row * 768;
    float acc = 0.0f;
#pragma unroll
    for (int i = 0; i < 12; ++i) {
        int k = lane + i * 64;
        acc = fmaf(wi[k], feat[k & 255], acc);
        acc = fmaf(wh[k], hx[k], acc);
    }
#pragma unroll
    for (int s = 32; s; s >>= 1) acc += __shfl_down(acc, s, 64);
    if (lane == 0) gates[row] = acc + bih[row] + bhh[row];
}

// ---------------- LSTM cell ----------------
__global__ void k_lstm_cell(const float* __restrict__ gates, const float* __restrict__ cx,
                            float* __restrict__ out, float* __restrict__ hxf) {
    int i = threadIdx.x;  // 768
    float g_i = gates[i], g_f = gates[768 + i], g_g = gates[1536 + i], g_o = gates[2304 + i];
    float c = cx[i];
    float cn = sigm(g_f) * c + sigm(g_i) * tanh_f(g_g);
    float hn = sigm(g_o) * tanh_f(cn);
    out[5 + i] = hn;
    out[5 + 768 + i] = cn;
    hxf[i] = hn;
}

// ---------------- heads ----------------
__global__ void k_heads(const float* __restrict__ hxf, const float* __restrict__ temb,
                        const int* __restrict__ tx, const float* __restrict__ cw,
                        const float* __restrict__ cb, const float* __restrict__ aw,
                        const float* __restrict__ ab, float* __restrict__ out) {
    __shared__ float z[800];
    int t = threadIdx.x;  // 320
    for (int i = t; i < 768; i += 320) z[i] = hxf[i];
    if (t < 32) z[768 + t] = temb[tx[0] * 32 + t];
    __syncthreads();
    int w = t >> 6, lane = t & 63;
    const float* row = (w == 0) ? cw : (aw + (size_t)(w - 1) * 800);
    float acc = 0.0f;
    for (int k = lane; k < 800; k += 64) acc = fmaf(row[k], z[k], acc);
#pragma unroll
    for (int s = 32; s; s >>= 1) acc += __shfl_down(acc, s, 64);
    if (lane == 0) {
        float b = (w == 0) ? cb[0] : ab[w - 1];
        out[w] = acc + b;
    }
}

extern "C" void kernel_launch(void* const* d_in, const int* in_sizes, int n_in,
                              void* d_out, int out_size, void* d_ws, size_t ws_size,
                              hipStream_t stream) {
    const float* x = (const float*)d_in[0];
    const int* curr = (const int*)d_in[1];
    const int* tx = (const int*)d_in[4];
    const float* hx = (const float*)d_in[5];
    const float* cx = (const float*)d_in[6];
    const float* c1w = (const float*)d_in[7];
    const float* c1b = (const float*)d_in[8];
    const float* c2w = (const float*)d_in[9];
    const float* c2b = (const float*)d_in[10];
    const float* c3w = (const float*)d_in[11];
    const float* c3b = (const float*)d_in[12];
    const float* emb = (const float*)d_in[13];
    const float* temb = (const float*)d_in[14];
    const float* gwih = (const float*)d_in[15];
    const float* gwhh = (const float*)d_in[16];
    const float* gbih = (const float*)d_in[17];
    const float* gbhh = (const float*)d_in[18];
    const float* attw = (const float*)d_in[19];
    const float* attb = (const float*)d_in[20];
    const float* linw = (const float*)d_in[21];
    const float* linb = (const float*)d_in[22];
    const float* lwih = (const float*)d_in[23];
    const float* lwhh = (const float*)d_in[24];
    const float* lbih = (const float*)d_in[25];
    const float* lbhh = (const float*)d_in[26];
    const float* cw = (const float*)d_in[27];
    const float* cb = (const float*)d_in[28];
    const float* aw = (const float*)d_in[29];
    const float* ab = (const float*)d_in[30];
    float* out = (float*)d_out;

    char* ws = (char*)d_ws;
    float* gi = (float*)(ws + 0);                 // 2048*768 f32
    float* h1 = (float*)(ws + 6291456);
    float* h2 = (float*)(ws + 6752256);
    float* x3 = (float*)(ws + 6802432);
    float* attn0 = (float*)(ws + 6811648);
    float* feat = (float*)(ws + 6811904);
    float* gates = (float*)(ws + 6812928);
    float* hxf = (float*)(ws + 6825216);
    uint32_t* wf16p = (uint32_t*)(ws + 6828288);  // 98304 u32 (f16-pair W_hh)

    k_pack<<<384, 256, 0, stream>>>(gwhh, wf16p);
    k_gi<<<6144, 256, 0, stream>>>(curr, emb, gwih, gbih, gi);
    k_conv1<<<450, 256, 0, stream>>>(x, c1w, c1b, h1);
    k_conv2<<<49, 256, 0, stream>>>(h1, c2w, c2b, h2);
    k_conv3<<<9, 256, 0, stream>>>(h2, c3w, c3b, x3);
    k_gru_scan<<<1, 256, 0, stream>>>(gi, wf16p, gbhh, attw, attb, attn0);
    k_feat<<<4, 64, 0, stream>>>(x3, attn0, linw, linb, feat);
    k_lstm_gates<<<768, 256, 0, stream>>>(lwih, lwhh, lbih, lbhh, hx, feat, gates);
    k_lstm_cell<<<1, 768, 0, stream>>>(gates, cx, out, hxf);
    k_heads<<<1, 320, 0, stream>>>(hxf, temb, tx, cw, cb, aw, ab, out);
}

// Round 6
// 2577.640 us; speedup vs baseline: 8.3793x; 1.3275x over previous
//
#include <hip/hip_runtime.h>
#include <hip/hip_bf16.h>
#include <stdint.h>

// a3c_lstm_ga forward, MI355X. Float tensors f32 (bf16-rounded values), ints
// int32. Output f32: [critic(1), actor(4), hx_new(768), cx_new(768)].
// Bug-faithful: only attn[0] consumed -> one GRU scan.
//
// R6: MFMA scan with 2 waves/SIMD. R5 used 1 wave/SIMD: per-SIMD floor is
// 96 mfma_16x16x32_f16 x ~16 cyc = 1536 cyc/step, and with no co-resident
// wave every ds_read/dep/barrier stall was exposed (observed 3690 cyc/step,
// on-CU MfmaUtil 41%). Now: 512 thr / 8 waves / waves_per_eu(2,2); wave w
// owns 96 rows = 6 N-tiles x 8 K-tiles = 48 MFMAs, B-frags = 192 laundered
// VGPRs (unified file), A-frag loads interleaved into the MFMA stream.
// h enters MFMA as A rows 0/1: row0 = h_hi (f16), row1 = (h-h_hi)*1024
// (dodges f16 subnormals); y = D[0][n] + D[1][n]/1024.

typedef _Float16 half8 __attribute__((ext_vector_type(8)));
typedef _Float16 half2v __attribute__((ext_vector_type(2)));
typedef float f32x4 __attribute__((ext_vector_type(4)));

__device__ __forceinline__ float sigm(float x) { return 1.0f / (1.0f + __expf(-x)); }
__device__ __forceinline__ float tanh_f(float x) { return 2.0f / (1.0f + __expf(-2.0f * x)) - 1.0f; }

// ---------------- pack W_hh f32 -> f16 pairs ----------------
__global__ void k_pack(const float* __restrict__ whh, uint32_t* __restrict__ wf16p) {
    int i = blockIdx.x * 256 + threadIdx.x;  // 98304 pairs
    if (i >= 98304) return;
    half2v p = {(_Float16)whh[2 * i], (_Float16)whh[2 * i + 1]};
    wf16p[i] = __builtin_bit_cast(uint32_t, p);
}

// ---------------- conv tower ----------------
__global__ void k_conv1(const float* __restrict__ x, const float* __restrict__ w,
                        const float* __restrict__ b, float* __restrict__ h1) {
    int idx = blockIdx.x * 256 + threadIdx.x;
    if (idx >= 128 * 30 * 30) return;
    int ox = idx % 30, oy = (idx / 30) % 30, oc = idx / 900;
    const float* wr = w + oc * 192;
    float acc = b[oc];
    for (int c = 0; c < 3; ++c)
        for (int ky = 0; ky < 8; ++ky) {
            const float* xr = x + (c * 124 + oy * 4 + ky) * 124 + ox * 4;
            const float* wk = wr + (c * 8 + ky) * 8;
#pragma unroll
            for (int kx = 0; kx < 8; ++kx) acc = fmaf(xr[kx], wk[kx], acc);
        }
    h1[idx] = fmaxf(acc, 0.0f);
}

__global__ void k_conv2(const float* __restrict__ h1, const float* __restrict__ w,
                        const float* __restrict__ b, float* __restrict__ h2) {
    int idx = blockIdx.x * 256 + threadIdx.x;
    if (idx >= 64 * 14 * 14) return;
    int ox = idx % 14, oy = (idx / 14) % 14, oc = idx / 196;
    float acc = b[oc];
    const float* wr = w + oc * 128 * 16;
    for (int c = 0; c < 128; ++c) {
#pragma unroll
        for (int ky = 0; ky < 4; ++ky) {
            const float* hr = h1 + (c * 30 + oy * 2 + ky) * 30 + ox * 2;
            const float* wk = wr + (c * 4 + ky) * 4;
#pragma unroll
            for (int kx = 0; kx < 4; ++kx) acc = fmaf(hr[kx], wk[kx], acc);
        }
    }
    h2[idx] = fmaxf(acc, 0.0f);
}

__global__ void k_conv3(const float* __restrict__ h2, const float* __restrict__ w,
                        const float* __restrict__ b, float* __restrict__ x3) {
    int idx = blockIdx.x * 256 + threadIdx.x;
    if (idx >= 64 * 6 * 6) return;
    int ox = idx % 6, oy = (idx / 6) % 6, oc = idx / 36;
    float acc = b[oc];
    const float* wr = w + oc * 64 * 16;
    for (int c = 0; c < 64; ++c) {
#pragma unroll
        for (int ky = 0; ky < 4; ++ky) {
            const float* hr = h2 + (c * 14 + oy * 2 + ky) * 14 + ox * 2;
            const float* wk = wr + (c * 4 + ky) * 4;
#pragma unroll
            for (int kx = 0; kx < 4; ++kx) acc = fmaf(hr[kx], wk[kx], acc);
        }
    }
    x3[idx] = fmaxf(acc, 0.0f);
}

// ---------------- GRU input-gate precompute ----------------
__global__ void k_gi(const int* __restrict__ curr, const float* __restrict__ emb,
                     const float* __restrict__ wih, const float* __restrict__ bih,
                     float* __restrict__ gi) {
    int idx = blockIdx.x * 256 + threadIdx.x;  // 2048*768
    int j = idx % 768, t = idx / 768;
    int tok = curr[t];
    const float4* e = (const float4*)(emb + tok * 32);
    const float4* wr = (const float4*)(wih + j * 32);
    float acc = bih[j];
#pragma unroll
    for (int k = 0; k < 8; ++k) {
        float4 ev = e[k], wv = wr[k];
        acc = fmaf(ev.x, wv.x, acc);
        acc = fmaf(ev.y, wv.y, acc);
        acc = fmaf(ev.z, wv.z, acc);
        acc = fmaf(ev.w, wv.w, acc);
    }
    gi[idx] = acc;
}

// ---------------- MFMA GRU scan: 512 thr, 8 waves, 2 waves/SIMD ----------------
#define FOR8(X, nt) X(nt, 0) X(nt, 1) X(nt, 2) X(nt, 3) X(nt, 4) X(nt, 5) X(nt, 6) X(nt, 7)
#define FOR6(Y) Y(0) Y(1) Y(2) Y(3) Y(4) Y(5)

#define DECLB(nt, kt) uint4 b##nt##_##kt;
#define DECLBROW(nt) FOR8(DECLB, nt)
#define LOADB(nt, kt) b##nt##_##kt = wp4[nt * 512 + kt * 4 + quad];
#define LOADBROW(nt) FOR8(LOADB, nt)
#define TIEB(nt, kt) \
    asm volatile("" : "+v"(b##nt##_##kt.x), "+v"(b##nt##_##kt.y), "+v"(b##nt##_##kt.z), "+v"(b##nt##_##kt.w));
#define TIEBROW(nt) FOR8(TIEB, nt)
#define DECLBIAS(nt) const float bias##nt = bhh[wbase + nt * 16 + n16];
#define DECLACC(nt) f32x4 acc##nt;
#define ZEROACC(nt) acc##nt = (f32x4)(0.0f);
#define MF(nt, kt) \
    acc##nt = __builtin_amdgcn_mfma_f32_16x16x32_f16(a##kt, __builtin_bit_cast(half8, b##nt##_##kt), acc##nt, 0, 0, 0);
#define MFK(kt) MF(0, kt) MF(1, kt) MF(2, kt) MF(3, kt) MF(4, kt) MF(5, kt)
#define LOADA(kt) half8 a##kt = __builtin_bit_cast(half8, abase[kt * 4 + quad]);
#define EPI(nt) \
    if (lane < 16) gh[wbase + nt * 16 + lane] = acc##nt.x + acc##nt.y * 0.0009765625f + bias##nt;

__global__ __attribute__((amdgpu_flat_work_group_size(512, 512), amdgpu_waves_per_eu(2, 2)))
void k_gru_scan(const float* __restrict__ gi, const uint32_t* __restrict__ wf16p,
                const float* __restrict__ bhh, const float* __restrict__ attn_w,
                const float* __restrict__ attn_b, float* __restrict__ attn0) {
    __shared__ __align__(16) _Float16 hhi[256];
    __shared__ __align__(16) _Float16 hlo[256];  // (h - hhi) * 1024
    __shared__ float gh[768];
    const int tid = threadIdx.x;   // 0..511
    const int lane = tid & 63;
    const int wv = tid >> 6;       // wave 0..7
    const int n16 = lane & 15;     // B col (output row-in-tile); also A row m
    const int quad = lane >> 4;    // k-subchunk selector
    const int wbase = wv * 96;     // this wave's first output row

    // B-frags: lane holds W[wbase + nt*16 + n16][kt*32 + quad*8 + j], j=0..7
    FOR6(DECLBROW)
    {
        const uint4* wp4 = (const uint4*)(wf16p + (size_t)(wbase + n16) * 128);
        FOR6(LOADBROW)
    }
    FOR6(TIEBROW)  // launder: cannot be rematerialized by re-loading
    FOR6(DECLBIAS)
    FOR6(DECLACC)

    float h_own = 0.0f;  // thread tid<256 owns h[tid]
    if (tid < 256) {
        hhi[tid] = (_Float16)0.0f;
        hlo[tid] = (_Float16)0.0f;
    }
    float gv0 = 0.f, gv1 = 0.f, gv2 = 0.f;
    if (tid < 256) {
        gv0 = gi[tid];
        gv1 = gi[256 + tid];
        gv2 = gi[512 + tid];
    }
    __syncthreads();

    const uint4* abase = (n16 == 1) ? (const uint4*)hlo : (const uint4*)hhi;

#pragma clang loop unroll(disable)
    for (int step = 0; step < 2048; ++step) {
        // prefetch next step's input gates; latency hides under MFMAs
        float gn0 = 0.f, gn1 = 0.f, gn2 = 0.f;
        if (step < 2047 && tid < 256) {
            const float* gp = gi + (size_t)(step + 1) * 768 + tid;
            gn0 = gp[0]; gn1 = gp[256]; gn2 = gp[512];
        }

        FOR6(ZEROACC)
        // A-frag loads interleaved with MFMA stream (peak ~2 live A-frags)
        LOADA(0) LOADA(1)
        MFK(0)
        LOADA(2)
        MFK(1)
        LOADA(3)
        MFK(2)
        LOADA(4)
        MFK(3)
        LOADA(5)
        MFK(4)
        LOADA(6)
        MFK(5)
        LOADA(7)
        MFK(6)
        MFK(7)

        // y[wbase+nt*16+col] = D[0][col] + D[1][col]/1024 + bhh  (lanes 0-15)
        FOR6(EPI)
        __syncthreads();

        // gate math: thread tid<256 handles element tid
        if (tid < 256) {
            float r = sigm(gv0 + gh[tid]);
            float z = sigm(gv1 + gh[256 + tid]);
            float n = tanh_f(fmaf(r, gh[512 + tid], gv2));
            h_own = fmaf(z, h_own - n, n);  // (1-z)*n + z*h
            _Float16 hi16 = (_Float16)h_own;
            hhi[tid] = hi16;
            hlo[tid] = (_Float16)((h_own - (float)hi16) * 1024.0f);
        }
        gv0 = gn0; gv1 = gn1; gv2 = gn2;
        __syncthreads();
    }

    // fused attention head: attn0[j] = sigm(attn_w[j] . h + attn_b[j]), j<64
    if (tid < 64) {
        const float* ar = attn_w + tid * 256;
        float acc = attn_b[tid];
        for (int k = 0; k < 256; ++k) {
            float hk = (float)hhi[k] + (float)hlo[k] * 0.0009765625f;
            acc = fmaf(ar[k], hk, acc);
        }
        attn0[tid] = sigm(acc);
    }
}

// ---------------- fuse + linear ----------------
__global__ void k_feat(const float* __restrict__ x3, const float* __restrict__ attn0,
                       const float* __restrict__ lw, const float* __restrict__ lb,
                       float* __restrict__ feat) {
    __shared__ __align__(16) float fused[2304];
    int t = threadIdx.x;  // 64
    for (int i = t; i < 2304; i += 64) fused[i] = x3[i] * attn0[i / 36];
    __syncthreads();
    int row = blockIdx.x * 64 + t;
    const float4* wvv = (const float4*)(lw + (size_t)row * 2304);
    float acc = lb[row];
    for (int i = 0; i < 576; ++i) {
        float4 v = wvv[i];
        const float* f = fused + i * 4;
        acc = fmaf(v.x, f[0], acc);
        acc = fmaf(v.y, f[1], acc);
        acc = fmaf(v.z, f[2], acc);
        acc = fmaf(v.w, f[3], acc);
    }
    feat[row] = fmaxf(acc, 0.0f);
}

// ---------------- LSTM gates ----------------
__global__ void k_lstm_gates(const float* __restrict__ wih, const float* __restrict__ whh,
                             const float* __restrict__ bih, const float* __restrict__ bhh,
                             const float* __restrict__ hx, const float* __restrict__ feat,
                             float* __restrict__ gates) {
    int wid = threadIdx.x >> 6, lane = threadIdx.x & 63;
    int row = blockIdx.x * 4 + wid;
    const float* wi = wih + (size_t)row * 768;
    const float* wh = whh + (size_t)row * 768;
    float acc = 0.0f;
#pragma unroll
    for (int i = 0; i < 12; ++i) {
        int k = lane + i * 64;
        acc = fmaf(wi[k], feat[k & 255], acc);
        acc = fmaf(wh[k], hx[k], acc);
    }
#pragma unroll
    for (int s = 32; s; s >>= 1) acc += __shfl_down(acc, s, 64);
    if (lane == 0) gates[row] = acc + bih[row] + bhh[row];
}

// ---------------- LSTM cell ----------------
__global__ void k_lstm_cell(const float* __restrict__ gates, const float* __restrict__ cx,
                            float* __restrict__ out, float* __restrict__ hxf) {
    int i = threadIdx.x;  // 768
    float g_i = gates[i], g_f = gates[768 + i], g_g = gates[1536 + i], g_o = gates[2304 + i];
    float c = cx[i];
    float cn = sigm(g_f) * c + sigm(g_i) * tanh_f(g_g);
    float hn = sigm(g_o) * tanh_f(cn);
    out[5 + i] = hn;
    out[5 + 768 + i] = cn;
    hxf[i] = hn;
}

// ---------------- heads ----------------
__global__ void k_heads(const float* __restrict__ hxf, const float* __restrict__ temb,
                        const int* __restrict__ tx, const float* __restrict__ cw,
                        const float* __restrict__ cb, const float* __restrict__ aw,
                        const float* __restrict__ ab, float* __restrict__ out) {
    __shared__ float z[800];
    int t = threadIdx.x;  // 320
    for (int i = t; i < 768; i += 320) z[i] = hxf[i];
    if (t < 32) z[768 + t] = temb[tx[0] * 32 + t];
    __syncthreads();
    int w = t >> 6, lane = t & 63;
    const float* row = (w == 0) ? cw : (aw + (size_t)(w - 1) * 800);
    float acc = 0.0f;
    for (int k = lane; k < 800; k += 64) acc = fmaf(row[k], z[k], acc);
#pragma unroll
    for (int s = 32; s; s >>= 1) acc += __shfl_down(acc, s, 64);
    if (lane == 0) {
        float b = (w == 0) ? cb[0] : ab[w - 1];
        out[w] = acc + b;
    }
}

extern "C" void kernel_launch(void* const* d_in, const int* in_sizes, int n_in,
                              void* d_out, int out_size, void* d_ws, size_t ws_size,
                              hipStream_t stream) {
    const float* x = (const float*)d_in[0];
    const int* curr = (const int*)d_in[1];
    const int* tx = (const int*)d_in[4];
    const float* hx = (const float*)d_in[5];
    const float* cx = (const float*)d_in[6];
    const float* c1w = (const float*)d_in[7];
    const float* c1b = (const float*)d_in[8];
    const float* c2w = (const float*)d_in[9];
    const float* c2b = (const float*)d_in[10];
    const float* c3w = (const float*)d_in[11];
    const float* c3b = (const float*)d_in[12];
    const float* emb = (const float*)d_in[13];
    const float* temb = (const float*)d_in[14];
    const float* gwih = (const float*)d_in[15];
    const float* gwhh = (const float*)d_in[16];
    const float* gbih = (const float*)d_in[17];
    const float* gbhh = (const float*)d_in[18];
    const float* attw = (const float*)d_in[19];
    const float* attb = (const float*)d_in[20];
    const float* linw = (const float*)d_in[21];
    const float* linb = (const float*)d_in[22];
    const float* lwih = (const float*)d_in[23];
    const float* lwhh = (const float*)d_in[24];
    const float* lbih = (const float*)d_in[25];
    const float* lbhh = (const float*)d_in[26];
    const float* cw = (const float*)d_in[27];
    const float* cb = (const float*)d_in[28];
    const float* aw = (const float*)d_in[29];
    const float* ab = (const float*)d_in[30];
    float* out = (float*)d_out;

    char* ws = (char*)d_ws;
    float* gi = (float*)(ws + 0);                 // 2048*768 f32
    float* h1 = (float*)(ws + 6291456);
    float* h2 = (float*)(ws + 6752256);
    float* x3 = (float*)(ws + 6802432);
    float* attn0 = (float*)(ws + 6811648);
    float* feat = (float*)(ws + 6811904);
    float* gates = (float*)(ws + 6812928);
    float* hxf = (float*)(ws + 6825216);
    uint32_t* wf16p = (uint32_t*)(ws + 6828288);  // 98304 u32 (f16-pair W_hh)

    k_pack<<<384, 256, 0, stream>>>(gwhh, wf16p);
    k_gi<<<6144, 256, 0, stream>>>(curr, emb, gwih, gbih, gi);
    k_conv1<<<450, 256, 0, stream>>>(x, c1w, c1b, h1);
    k_conv2<<<49, 256, 0, stream>>>(h1, c2w, c2b, h2);
    k_conv3<<<9, 256, 0, stream>>>(h2, c3w, c3b, x3);
    k_gru_scan<<<1, 512, 0, stream>>>(gi, wf16p, gbhh, attw, attb, attn0);
    k_feat<<<4, 64, 0, stream>>>(x3, attn0, linw, linb, feat);
    k_lstm_gates<<<768, 256, 0, stream>>>(lwih, lwhh, lbih, lbhh, hx, feat, gates);
    k_lstm_cell<<<1, 768, 0, stream>>>(gates, cx, out, hxf);
    k_heads<<<1, 320, 0, stream>>>(hxf, temb, tx, cw, cb, aw, ab, out);
}